// Round 7
// baseline (116.583 us; speedup 1.0000x reference)
//
#include <hip/hip_runtime.h>
#include <cstdint>

// Problem constants (B=1024, S=4096, P=512)
constexpr int B_ = 1024;
constexpr int S_ = 4096;
constexpr int P_ = 512;
constexpr int NSCAT = 512;   // scatter blocks (partial-histogram rows)

// MEASUREMENT ROUND: amplification factors (identical work repeated; the
// opaque zero offset defeats hoisting). Final state unchanged.
constexpr int SCAT_REP = 8;
constexpr int RED_REP  = 32;
constexpr int EVAL_REP = 12;

// Fixed-point scale for packed LDS accumulation: sum in low 48 bits
// (ds * 2^21), count in high 16 bits. One native ds_add_u64 per element.
constexpr float FPSCALE = 2097152.0f;          // 2^21
constexpr double INV_FPSCALE = 1.0 / 2097152.0;

// ---------------------------------------------------------------------------
// Kernel A: per-block histogram, repeated SCAT_REP times for profiling.
// ---------------------------------------------------------------------------
__global__ __launch_bounds__(256) void scatter_kernel(
    const int* __restrict__ idx, const float* __restrict__ ds,
    float* __restrict__ part, const int* __restrict__ padp) {
  __shared__ unsigned long long acc[4][P_];   // 16 KB
  const int t = threadIdx.x;
  const int w = t >> 6;
  const size_t oz = (size_t)(padp[0] >> 30);  // runtime 0, opaque to compiler

#pragma unroll 1
  for (int rep = 0; rep < SCAT_REP; ++rep) {
    const size_t ro = oz * (size_t)rep;
#pragma unroll
    for (int c = 0; c < 4; ++c) {
      acc[c][t] = 0ull; acc[c][t + 256] = 0ull;
    }
    __syncthreads();

    unsigned long long* __restrict__ ma = acc[w];
    const size_t base = (size_t)blockIdx.x * 8192 + (size_t)t * 4 + ro;
#pragma unroll
    for (int k = 0; k < 8; k += 2) {
      const size_t off0 = base + (size_t)k * 1024;
      const size_t off1 = off0 + 1024;
      int4   i0 = *reinterpret_cast<const int4*>(idx + off0);
      int4   i1 = *reinterpret_cast<const int4*>(idx + off1);
      float4 d0 = *reinterpret_cast<const float4*>(ds + off0);
      float4 d1 = *reinterpret_cast<const float4*>(ds + off1);
      atomicAdd(&ma[i0.x], (1ull << 48) | (unsigned long long)(d0.x * FPSCALE));
      atomicAdd(&ma[i0.y], (1ull << 48) | (unsigned long long)(d0.y * FPSCALE));
      atomicAdd(&ma[i0.z], (1ull << 48) | (unsigned long long)(d0.z * FPSCALE));
      atomicAdd(&ma[i0.w], (1ull << 48) | (unsigned long long)(d0.w * FPSCALE));
      atomicAdd(&ma[i1.x], (1ull << 48) | (unsigned long long)(d1.x * FPSCALE));
      atomicAdd(&ma[i1.y], (1ull << 48) | (unsigned long long)(d1.y * FPSCALE));
      atomicAdd(&ma[i1.z], (1ull << 48) | (unsigned long long)(d1.z * FPSCALE));
      atomicAdd(&ma[i1.w], (1ull << 48) | (unsigned long long)(d1.w * FPSCALE));
    }
    __syncthreads();

    const int b0 = 2 * t, b1 = 2 * t + 1;
    const unsigned long long v0 =
        acc[0][b0] + acc[1][b0] + acc[2][b0] + acc[3][b0];
    const unsigned long long v1 =
        acc[0][b1] + acc[1][b1] + acc[2][b1] + acc[3][b1];
    const unsigned long long MASK48 = (1ull << 48) - 1;
    float4 ov;
    ov.x = (float)((double)(v0 & MASK48) * INV_FPSCALE);
    ov.y = (float)(v0 >> 48);
    ov.z = (float)((double)(v1 & MASK48) * INV_FPSCALE);
    ov.w = (float)(v1 >> 48);
    *reinterpret_cast<float4*>(part + (size_t)blockIdx.x * 1024 + 4 * t + ro)
        = ov;
    __syncthreads();   // flush reads acc; next rep re-zeroes it
  }
}

// ---------------------------------------------------------------------------
// Kernel B: one block per BIN, repeated RED_REP times for profiling.
// ---------------------------------------------------------------------------
__global__ __launch_bounds__(256) void reduce_finalize_kernel(
    const float* __restrict__ part,
    const float* __restrict__ sum_in, const float* __restrict__ cnt_in,
    const float* __restrict__ dur_in,
    float* __restrict__ table, float* __restrict__ stats,
    float* __restrict__ out_tail, const int* __restrict__ padp) {
  __shared__ float2 sred[256];
  const int t = threadIdx.x;
  const int p = blockIdx.x;
  const size_t oz = (size_t)(padp[0] >> 30);

#pragma unroll 1
  for (int rep = 0; rep < RED_REP; ++rep) {
    const size_t ro = oz * (size_t)rep;
    const float2 a = *reinterpret_cast<const float2*>(
        part + (size_t)t * 1024 + 2 * p + ro);
    const float2 b = *reinterpret_cast<const float2*>(
        part + (size_t)(t + 256) * 1024 + 2 * p + ro);
    sred[t] = make_float2(a.x + b.x, a.y + b.y);
    __syncthreads();

    if (t < 128) {
      sred[t].x += sred[t + 128].x;
      sred[t].y += sred[t + 128].y;
    }
    __syncthreads();

    if (t < 64) {
      float ss = sred[t].x + sred[t + 64].x;
      float cc = sred[t].y + sred[t + 64].y;
#pragma unroll
      for (int o = 32; o > 0; o >>= 1) {
        ss += __shfl_down(ss, o);
        cc += __shfl_down(cc, o);
      }
      if (t == 0) {
        const float sn = ss + sum_in[p];
        const float cn = cc + cnt_in[p];
        const float tv = (cc > 0.f) ? sn / fmaxf(cn, 1.f) : dur_in[p];
        table[p + ro]    = tv;
        out_tail[p + ro] = tv;
        if (p >= 2 && p < 7) {
          stats[p - 2 + ro]      = sn;
          stats[5 + p - 2 + ro]  = cn;
          stats[10 + p - 2 + ro] = cc;
        }
      }
    }
    __syncthreads();
  }
}

// ---------------------------------------------------------------------------
// Kernel C: per-row gather + rescale, repeated EVAL_REP times for profiling.
// ---------------------------------------------------------------------------
__global__ __launch_bounds__(256) void eval_kernel(
    const int* __restrict__ idx, const float* __restrict__ table,
    const float* __restrict__ stats, const float* __restrict__ rv,
    const float* __restrict__ dn_in, const int* __restrict__ padp,
    float* __restrict__ out) {
  __shared__ float tbl[P_];
  __shared__ int   red_a[4], red_b[4], red_c[4];
  __shared__ int   bcast[3];
  __shared__ float fbcast[2];

  const int t   = threadIdx.x;
  const int row = blockIdx.x;
  const int pad = padp[0];
  const size_t oz = (size_t)(pad >> 30);

#pragma unroll 1
  for (int rep = 0; rep < EVAL_REP; ++rep) {
    const size_t ro = oz * (size_t)rep;
    tbl[t]       = table[t + ro];
    tbl[t + 256] = table[t + 256 + ro];

    if (t == 0) {
      float ss = 0.f, cc = 0.f, rc = 0.f;
#pragma unroll
      for (int i = 0; i < 5; ++i) {
        ss += stats[i + ro]; cc += stats[5 + i + ro]; rc += stats[10 + i + ro];
      }
      const float dnn = (rc > 0.f) ? (ss / cc) : dn_in[0];
      const float dni = truncf(dnn);
      fbcast[0] = dni;
      fbcast[1] = dni - truncf(rv[0] * dnn);
      if (row == 0) out[(size_t)B_ * S_ + P_ + ro] = dnn;
    }
    __syncthreads();

    const int* __restrict__ rowidx = idx + (size_t)row * S_ + ro;
    int d[16];
    int jfirst = 0x7fffffff;
    int dmax   = 0x80000000;

#pragma unroll
    for (int k = 0; k < 4; ++k) {
      const int j0 = k * 1024 + t * 4;
      int4 iv = *reinterpret_cast<const int4*>(rowidx + j0);
      const int ivm[4] = {iv.x, iv.y, iv.z, iv.w};
#pragma unroll
      for (int m = 0; m < 4; ++m) {
        const int j = j0 + m;
        const int dd = (int)tbl[ivm[m]];
        d[k * 4 + m] = dd;
        if (j >= 1) {
          if (ivm[m] == pad && j < jfirst) jfirst = j;
          if (dd > dmax) dmax = dd;
        }
      }
    }

    const int wid = t >> 6, lane = t & 63;
    int a = jfirst, b = dmax;
#pragma unroll
    for (int o = 32; o > 0; o >>= 1) {
      a = min(a, __shfl_down(a, o));
      b = max(b, __shfl_down(b, o));
    }
    if (lane == 0) { red_a[wid] = a; red_b[wid] = b; }
    __syncthreads();
    if (t == 0) {
      int na = min(min(red_a[0], red_a[1]), min(red_a[2], red_a[3]));
      int nb = max(max(red_b[0], red_b[1]), max(red_b[2], red_b[3]));
      bcast[0] = (na == 0x7fffffff) ? 1 : na;
      bcast[1] = nb;
    }
    __syncthreads();
    const int n       = bcast[0];
    const int dmaxall = bcast[1];

    int dsum = 0;
#pragma unroll
    for (int k = 0; k < 4; ++k) {
      const int j0 = k * 1024 + t * 4;
#pragma unroll
      for (int m = 0; m < 4; ++m) {
        const int j = j0 + m;
        if (j >= 1 && j < n) dsum += d[k * 4 + m];
      }
    }
#pragma unroll
    for (int o = 32; o > 0; o >>= 1) dsum += __shfl_down(dsum, o);
    if (lane == 0) red_c[wid] = dsum;
    __syncthreads();
    if (t == 0) bcast[2] = red_c[0] + red_c[1] + red_c[2] + red_c[3];
    __syncthreads();
    const int denom = bcast[2];

    const float dni = fbcast[0];
    const float num = fbcast[1];
    const float denomf = (float)denom;
    const float rc = (n == 1) ? 1.0f
                              : fminf(1.0f, num / (denomf > 0.f ? denomf : 1.0f));
    const int delta = max(dmaxall, 1);
    const int dur0  = max(1, (int)dni - delta);

    float* __restrict__ rowout = out + (size_t)row * S_ + ro;
#pragma unroll
    for (int k = 0; k < 4; ++k) {
      const int j0 = k * 1024 + t * 4;
      float4 ov;
      float* o = reinterpret_cast<float*>(&ov);
#pragma unroll
      for (int m = 0; m < 4; ++m) {
        const int j = j0 + m;
        const int dd = d[k * 4 + m];
        int v;
        if (j == 0)      v = dur0;
        else if (j < n)  v = max(1, (int)truncf(rc * (float)dd));
        else             v = dd;
        o[m] = (float)v;
      }
      *reinterpret_cast<float4*>(rowout + j0) = ov;
    }
    __syncthreads();
  }
}

// ---------------------------------------------------------------------------
extern "C" void kernel_launch(void* const* d_in, const int* in_sizes, int n_in,
                              void* d_out, int out_size, void* d_ws, size_t ws_size,
                              hipStream_t stream) {
  const int*   idx    = (const int*)d_in[0];
  const float* ds     = (const float*)d_in[1];
  const float* sum_in = (const float*)d_in[2];
  const float* cnt_in = (const float*)d_in[3];
  const float* dur_in = (const float*)d_in[4];
  const float* rv     = (const float*)d_in[5];
  const float* dn     = (const float*)d_in[6];
  const int*   pad    = (const int*)d_in[7];

  float* out = (float*)d_out;

  float* part  = (float*)d_ws;                 // [512][1024] = 2 MB
  float* table = part + (size_t)NSCAT * 1024;  // [512]
  float* stats = table + P_;                   // [15]

  scatter_kernel<<<NSCAT, 256, 0, stream>>>(idx, ds, part, pad);
  reduce_finalize_kernel<<<P_, 256, 0, stream>>>(part, sum_in, cnt_in, dur_in,
                                                 table, stats,
                                                 out + (size_t)B_ * S_, pad);
  eval_kernel<<<1024, 256, 0, stream>>>(idx, table, stats, rv, dn, pad, out);
}

// Round 8
// 36.113 us; speedup vs baseline: 3.2283x; 3.2283x over previous
//
#include <hip/hip_runtime.h>
#include <cstdint>

// Problem constants (B=1024, S=4096, P=512)
constexpr int B_ = 1024;
constexpr int S_ = 4096;
constexpr int P_ = 512;
constexpr int NSCAT = 512;   // scatter blocks (2 rows each)
constexpr int ASTRIDE = 8;   // u64 stride: one accumulator per 64B line

// Fixed-point packing: count in bits 48..63, sum*2^21 in bits 0..47.
// Bounds: per-bin global cnt ~8.2K << 2^16; sum < 8.6K*20*2^21 ~ 3.6e11 << 2^48.
constexpr float FPSCALE = 2097152.0f;          // 2^21
constexpr double INV_FPSCALE = 1.0 / 2097152.0;

// ---------------------------------------------------------------------------
// Kernel A: per-block LDS u64 histogram (per-wave sub-hists), flushed with
// ONE device-scope u64 atomic per bin into the strided global accumulator.
// Integer atomics -> order-independent -> bit-deterministic.
// ---------------------------------------------------------------------------
__global__ __launch_bounds__(256) void scatter_kernel(
    const int* __restrict__ idx, const float* __restrict__ ds,
    unsigned long long* __restrict__ acc) {
  __shared__ unsigned long long lacc[4][P_];   // 16 KB
  const int t = threadIdx.x;
  const int w = t >> 6;
#pragma unroll
  for (int c = 0; c < 4; ++c) {
    lacc[c][t] = 0ull; lacc[c][t + 256] = 0ull;
  }
  __syncthreads();

  unsigned long long* __restrict__ ma = lacc[w];
  const size_t base = (size_t)blockIdx.x * 8192 + (size_t)t * 4;
#pragma unroll
  for (int k = 0; k < 8; k += 2) {
    const size_t off0 = base + (size_t)k * 1024;
    const size_t off1 = off0 + 1024;
    int4   i0 = *reinterpret_cast<const int4*>(idx + off0);
    int4   i1 = *reinterpret_cast<const int4*>(idx + off1);
    float4 d0 = *reinterpret_cast<const float4*>(ds + off0);
    float4 d1 = *reinterpret_cast<const float4*>(ds + off1);
    atomicAdd(&ma[i0.x], (1ull << 48) | (unsigned long long)(d0.x * FPSCALE));
    atomicAdd(&ma[i0.y], (1ull << 48) | (unsigned long long)(d0.y * FPSCALE));
    atomicAdd(&ma[i0.z], (1ull << 48) | (unsigned long long)(d0.z * FPSCALE));
    atomicAdd(&ma[i0.w], (1ull << 48) | (unsigned long long)(d0.w * FPSCALE));
    atomicAdd(&ma[i1.x], (1ull << 48) | (unsigned long long)(d1.x * FPSCALE));
    atomicAdd(&ma[i1.y], (1ull << 48) | (unsigned long long)(d1.y * FPSCALE));
    atomicAdd(&ma[i1.z], (1ull << 48) | (unsigned long long)(d1.z * FPSCALE));
    atomicAdd(&ma[i1.w], (1ull << 48) | (unsigned long long)(d1.w * FPSCALE));
  }
  __syncthreads();

  // flush: thread t owns bins 2t, 2t+1 -> 2 global u64 atomics (64B-strided)
  const int b0 = 2 * t, b1 = 2 * t + 1;
  const unsigned long long v0 =
      lacc[0][b0] + lacc[1][b0] + lacc[2][b0] + lacc[3][b0];
  const unsigned long long v1 =
      lacc[0][b1] + lacc[1][b1] + lacc[2][b1] + lacc[3][b1];
  if (v0) atomicAdd(&acc[(size_t)b0 * ASTRIDE], v0);
  if (v1) atomicAdd(&acc[(size_t)b1 * ASTRIDE], v1);
}

// ---------------------------------------------------------------------------
// Kernel B: eval. Each block decodes the 4KB accumulator inline into its LDS
// table (2 u64 loads + 2 divides/thread, L2-hot), computes the dn scalars,
// then does the per-row gather + rescale. Block 0 writes the table tail + dn.
// ---------------------------------------------------------------------------
__global__ __launch_bounds__(256) void eval_kernel(
    const int* __restrict__ idx, const unsigned long long* __restrict__ acc,
    const float* __restrict__ sum_in, const float* __restrict__ cnt_in,
    const float* __restrict__ dur_in, const float* __restrict__ rv,
    const float* __restrict__ dn_in, const int* __restrict__ padp,
    float* __restrict__ out) {
  __shared__ float tbl[P_];
  __shared__ int   red_a[4], red_b[4], red_c[4];
  __shared__ int   bcast[3];   // n, dmax, denom
  __shared__ float fbcast[2];  // dni, num

  const int t   = threadIdx.x;
  const int row = blockIdx.x;
  const int pad = padp[0];
  const unsigned long long MASK48 = (1ull << 48) - 1;

  // ---- decode accumulator -> LDS table (bins t and t+256) ----
  {
    const unsigned long long v0 = acc[(size_t)t * ASTRIDE];
    const unsigned long long v1 = acc[(size_t)(t + 256) * ASTRIDE];
    const float c0 = (float)(v0 >> 48);
    const float c1 = (float)(v1 >> 48);
    const float s0 = (float)((double)(v0 & MASK48) * INV_FPSCALE);
    const float s1 = (float)((double)(v1 & MASK48) * INV_FPSCALE);
    const float sn0 = s0 + sum_in[t];
    const float sn1 = s1 + sum_in[t + 256];
    const float cn0 = c0 + cnt_in[t];
    const float cn1 = c1 + cnt_in[t + 256];
    const float tv0 = (c0 > 0.f) ? sn0 / fmaxf(cn0, 1.f) : dur_in[t];
    const float tv1 = (c1 > 0.f) ? sn1 / fmaxf(cn1, 1.f) : dur_in[t + 256];
    tbl[t]       = tv0;
    tbl[t + 256] = tv1;
    if (row == 0) {                       // duration_new output tail
      out[(size_t)B_ * S_ + t]       = tv0;
      out[(size_t)B_ * S_ + t + 256] = tv1;
    }
  }

  if (t == 0) {  // dn scalars from bins 2..6
    float ss = 0.f, cc = 0.f, rc = 0.f;
#pragma unroll
    for (int i = 2; i < 7; ++i) {
      const unsigned long long v = acc[(size_t)i * ASTRIDE];
      const float craw = (float)(v >> 48);
      ss += (float)((double)(v & MASK48) * INV_FPSCALE) + sum_in[i];
      cc += craw + cnt_in[i];
      rc += craw;
    }
    const float dnn = (rc > 0.f) ? (ss / cc) : dn_in[0];
    const float dni = truncf(dnn);
    fbcast[0] = dni;
    fbcast[1] = dni - truncf(rv[0] * dnn);   // num = int(dn) - int(rv*dn)
    if (row == 0) out[(size_t)B_ * S_ + P_] = dnn;  // dn_new output
  }
  __syncthreads();

  // ---- per-row gather ----
  const int* __restrict__ rowidx = idx + (size_t)row * S_;
  int d[16];
  int jfirst = 0x7fffffff;
  int dmax   = 0x80000000;

#pragma unroll
  for (int k = 0; k < 4; ++k) {
    const int j0 = k * 1024 + t * 4;
    int4 iv = *reinterpret_cast<const int4*>(rowidx + j0);
    const int ivm[4] = {iv.x, iv.y, iv.z, iv.w};
#pragma unroll
    for (int m = 0; m < 4; ++m) {
      const int j = j0 + m;
      const int dd = (int)tbl[ivm[m]];  // trunc-toward-zero, values >= 0
      d[k * 4 + m] = dd;
      if (j >= 1) {
        if (ivm[m] == pad && j < jfirst) jfirst = j;
        if (dd > dmax) dmax = dd;
      }
    }
  }

  // phase-1 reduce: min(jfirst), max(dmax) over 256 threads
  const int wid = t >> 6, lane = t & 63;
  int a = jfirst, b = dmax;
#pragma unroll
  for (int o = 32; o > 0; o >>= 1) {
    a = min(a, __shfl_down(a, o));
    b = max(b, __shfl_down(b, o));
  }
  if (lane == 0) { red_a[wid] = a; red_b[wid] = b; }
  __syncthreads();
  if (t == 0) {
    int na = min(min(red_a[0], red_a[1]), min(red_a[2], red_a[3]));
    int nb = max(max(red_b[0], red_b[1]), max(red_b[2], red_b[3]));
    bcast[0] = (na == 0x7fffffff) ? 1 : na;   // n
    bcast[1] = nb;                            // row max dur (j>=1)
  }
  __syncthreads();
  const int n       = bcast[0];
  const int dmaxall = bcast[1];

  // phase-2 reduce: denom = sum of d[j] for 1 <= j < n
  int dsum = 0;
#pragma unroll
  for (int k = 0; k < 4; ++k) {
    const int j0 = k * 1024 + t * 4;
#pragma unroll
    for (int m = 0; m < 4; ++m) {
      const int j = j0 + m;
      if (j >= 1 && j < n) dsum += d[k * 4 + m];
    }
  }
#pragma unroll
  for (int o = 32; o > 0; o >>= 1) dsum += __shfl_down(dsum, o);
  if (lane == 0) red_c[wid] = dsum;
  __syncthreads();
  if (t == 0) bcast[2] = red_c[0] + red_c[1] + red_c[2] + red_c[3];
  __syncthreads();
  const int denom = bcast[2];

  const float dni = fbcast[0];
  const float num = fbcast[1];
  const float denomf = (float)denom;
  const float rc = (n == 1) ? 1.0f
                            : fminf(1.0f, num / (denomf > 0.f ? denomf : 1.0f));
  const int delta = max(dmaxall, 1);
  const int dur0  = max(1, (int)dni - delta);

  float* __restrict__ rowout = out + (size_t)row * S_;
#pragma unroll
  for (int k = 0; k < 4; ++k) {
    const int j0 = k * 1024 + t * 4;
    float4 ov;
    float* o = reinterpret_cast<float*>(&ov);
#pragma unroll
    for (int m = 0; m < 4; ++m) {
      const int j = j0 + m;
      const int dd = d[k * 4 + m];
      int v;
      if (j == 0)      v = dur0;
      else if (j < n)  v = max(1, (int)truncf(rc * (float)dd));
      else             v = dd;
      o[m] = (float)v;
    }
    *reinterpret_cast<float4*>(rowout + j0) = ov;
  }
}

// ---------------------------------------------------------------------------
extern "C" void kernel_launch(void* const* d_in, const int* in_sizes, int n_in,
                              void* d_out, int out_size, void* d_ws, size_t ws_size,
                              hipStream_t stream) {
  const int*   idx    = (const int*)d_in[0];
  const float* ds     = (const float*)d_in[1];
  const float* sum_in = (const float*)d_in[2];
  const float* cnt_in = (const float*)d_in[3];
  const float* dur_in = (const float*)d_in[4];
  const float* rv     = (const float*)d_in[5];
  const float* dn     = (const float*)d_in[6];
  const int*   pad    = (const int*)d_in[7];

  float* out = (float*)d_out;
  unsigned long long* acc = (unsigned long long*)d_ws;  // [512*8] u64 = 32 KB

  hipMemsetAsync(acc, 0, (size_t)P_ * ASTRIDE * sizeof(unsigned long long),
                 stream);
  scatter_kernel<<<NSCAT, 256, 0, stream>>>(idx, ds, acc);
  eval_kernel<<<B_, 256, 0, stream>>>(idx, acc, sum_in, cnt_in, dur_in,
                                      rv, dn, pad, out);
}

// Round 9
// 25.421 us; speedup vs baseline: 4.5860x; 1.4206x over previous
//
#include <hip/hip_runtime.h>
#include <cstdint>

// Problem constants (B=1024, S=4096, P=512)
constexpr int B_ = 1024;
constexpr int S_ = 4096;
constexpr int P_ = 512;
constexpr int NSCAT = 512;   // scatter blocks (partial-histogram rows)

// Fixed-point scale for packed LDS accumulation: sum in low 48 bits
// (ds * 2^21), count in high 16 bits. One native ds_add_u64 per element.
constexpr float FPSCALE = 2097152.0f;          // 2^21
constexpr double INV_FPSCALE = 1.0 / 2097152.0;

// ---------------------------------------------------------------------------
// Kernel A: per-block histogram of (sum ds, count) over P=512 bins.
// 512 blocks x 256 threads x 32 elements = B*S exactly.
// Per-WAVE packed u64 LDS sub-histograms (4 copies): one atomicAdd(u64)
// per element -> guaranteed-native ds_add_u64 (no fp CAS-loop risk; this
// was the round-6 win: 43 -> 25.7 us vs f32 LDS atomicAdd CAS loops).
// Output: part[block][1024] interleaved {sum[bin], cnt[bin]} float pairs,
// written non-atomically (coalesced float4) -- device atomics measured
// ~50-100cy/op serialized per line (rounds 1/8), partials avoid them.
// ---------------------------------------------------------------------------
__global__ __launch_bounds__(256) void scatter_kernel(
    const int* __restrict__ idx, const float* __restrict__ ds,
    float* __restrict__ part) {
  __shared__ unsigned long long acc[4][P_];   // 16 KB
  const int t = threadIdx.x;
  const int w = t >> 6;
#pragma unroll
  for (int c = 0; c < 4; ++c) {
    acc[c][t] = 0ull; acc[c][t + 256] = 0ull;
  }
  __syncthreads();

  unsigned long long* __restrict__ ma = acc[w];
  const size_t base = (size_t)blockIdx.x * 8192 + (size_t)t * 4;
#pragma unroll
  for (int k = 0; k < 8; k += 2) {
    const size_t off0 = base + (size_t)k * 1024;
    const size_t off1 = off0 + 1024;
    int4   i0 = *reinterpret_cast<const int4*>(idx + off0);
    int4   i1 = *reinterpret_cast<const int4*>(idx + off1);
    float4 d0 = *reinterpret_cast<const float4*>(ds + off0);
    float4 d1 = *reinterpret_cast<const float4*>(ds + off1);
    atomicAdd(&ma[i0.x], (1ull << 48) | (unsigned long long)(d0.x * FPSCALE));
    atomicAdd(&ma[i0.y], (1ull << 48) | (unsigned long long)(d0.y * FPSCALE));
    atomicAdd(&ma[i0.z], (1ull << 48) | (unsigned long long)(d0.z * FPSCALE));
    atomicAdd(&ma[i0.w], (1ull << 48) | (unsigned long long)(d0.w * FPSCALE));
    atomicAdd(&ma[i1.x], (1ull << 48) | (unsigned long long)(d1.x * FPSCALE));
    atomicAdd(&ma[i1.y], (1ull << 48) | (unsigned long long)(d1.y * FPSCALE));
    atomicAdd(&ma[i1.z], (1ull << 48) | (unsigned long long)(d1.z * FPSCALE));
    atomicAdd(&ma[i1.w], (1ull << 48) | (unsigned long long)(d1.w * FPSCALE));
  }
  __syncthreads();

  // thread t flushes bins 2t and 2t+1 as one float4 (coalesced, deterministic)
  const int b0 = 2 * t, b1 = 2 * t + 1;
  const unsigned long long v0 =
      acc[0][b0] + acc[1][b0] + acc[2][b0] + acc[3][b0];
  const unsigned long long v1 =
      acc[0][b1] + acc[1][b1] + acc[2][b1] + acc[3][b1];
  const unsigned long long MASK48 = (1ull << 48) - 1;
  float4 ov;
  ov.x = (float)((double)(v0 & MASK48) * INV_FPSCALE);
  ov.y = (float)(v0 >> 48);
  ov.z = (float)((double)(v1 & MASK48) * INV_FPSCALE);
  ov.w = (float)(v1 >> 48);
  *reinterpret_cast<float4*>(part + (size_t)blockIdx.x * 1024 + 4 * t) = ov;
}

// ---------------------------------------------------------------------------
// Kernel B: one block per BIN (512 blocks x 256 threads). Thread t loads
// float2 {sum,cnt} at rows t and t+256 of its bin's column pair (2
// independent 8B loads, L2/L3-served), then LDS + shfl tree reduction.
// Thread 0 finalizes table[p]; bins 2..6 dump {sn, cn, raw_cnt} to stats.
// ---------------------------------------------------------------------------
__global__ __launch_bounds__(256) void reduce_finalize_kernel(
    const float* __restrict__ part,
    const float* __restrict__ sum_in, const float* __restrict__ cnt_in,
    const float* __restrict__ dur_in,
    float* __restrict__ table, float* __restrict__ stats,
    float* __restrict__ out_tail /* d_out + B*S : 512 table values */) {
  __shared__ float2 sred[256];
  const int t = threadIdx.x;
  const int p = blockIdx.x;

  const float2 a = *reinterpret_cast<const float2*>(
      part + (size_t)t * 1024 + 2 * p);
  const float2 b = *reinterpret_cast<const float2*>(
      part + (size_t)(t + 256) * 1024 + 2 * p);
  sred[t] = make_float2(a.x + b.x, a.y + b.y);
  __syncthreads();

  if (t < 128) {
    sred[t].x += sred[t + 128].x;
    sred[t].y += sred[t + 128].y;
  }
  __syncthreads();

  if (t < 64) {
    float ss = sred[t].x + sred[t + 64].x;
    float cc = sred[t].y + sred[t + 64].y;
#pragma unroll
    for (int o = 32; o > 0; o >>= 1) {
      ss += __shfl_down(ss, o);
      cc += __shfl_down(cc, o);
    }
    if (t == 0) {
      const float sn = ss + sum_in[p];
      const float cn = cc + cnt_in[p];
      const float tv = (cc > 0.f) ? sn / fmaxf(cn, 1.f) : dur_in[p];
      table[p]    = tv;
      out_tail[p] = tv;
      if (p >= 2 && p < 7) {
        stats[p - 2]      = sn;   // sum_new
        stats[5 + p - 2]  = cn;   // cnt_new
        stats[10 + p - 2] = cc;   // raw scatter count (for has_26)
      }
    }
  }
}

// ---------------------------------------------------------------------------
// Kernel C: per-row gather + rescale. 1 block (256 thr) per row; 16 cols/thr.
// Thread 0 of each block computes the dn scalars from stats (cheap, uniform);
// block 0 also writes dn_new to the output tail.
// ---------------------------------------------------------------------------
__global__ __launch_bounds__(256) void eval_kernel(
    const int* __restrict__ idx, const float* __restrict__ table,
    const float* __restrict__ stats, const float* __restrict__ rv,
    const float* __restrict__ dn_in, const int* __restrict__ padp,
    float* __restrict__ out) {
  __shared__ float tbl[P_];
  __shared__ int   red_a[4], red_b[4], red_c[4];
  __shared__ int   bcast[3];   // n, dmax, denom
  __shared__ float fbcast[2];  // dni, num

  const int t   = threadIdx.x;
  const int row = blockIdx.x;
  tbl[t]       = table[t];
  tbl[t + 256] = table[t + 256];
  const int pad = padp[0];

  if (t == 0) {
    float ss = 0.f, cc = 0.f, rc = 0.f;
#pragma unroll
    for (int i = 0; i < 5; ++i) {
      ss += stats[i]; cc += stats[5 + i]; rc += stats[10 + i];
    }
    const float dnn = (rc > 0.f) ? (ss / cc) : dn_in[0];
    const float dni = truncf(dnn);
    fbcast[0] = dni;
    fbcast[1] = dni - truncf(rv[0] * dnn);   // num = int(dn) - int(rv*dn)
    if (row == 0) out[(size_t)B_ * S_ + P_] = dnn;  // dn_new output
  }
  __syncthreads();

  const int* __restrict__ rowidx = idx + (size_t)row * S_;
  int d[16];
  int jfirst = 0x7fffffff;
  int dmax   = 0x80000000;

#pragma unroll
  for (int k = 0; k < 4; ++k) {
    const int j0 = k * 1024 + t * 4;
    int4 iv = *reinterpret_cast<const int4*>(rowidx + j0);
    const int ivm[4] = {iv.x, iv.y, iv.z, iv.w};
#pragma unroll
    for (int m = 0; m < 4; ++m) {
      const int j = j0 + m;
      const int dd = (int)tbl[ivm[m]];  // trunc-toward-zero, values >= 0
      d[k * 4 + m] = dd;
      if (j >= 1) {
        if (ivm[m] == pad && j < jfirst) jfirst = j;
        if (dd > dmax) dmax = dd;
      }
    }
  }

  // phase-1 reduce: min(jfirst), max(dmax) over 256 threads
  const int wid = t >> 6, lane = t & 63;
  int a = jfirst, b = dmax;
#pragma unroll
  for (int o = 32; o > 0; o >>= 1) {
    a = min(a, __shfl_down(a, o));
    b = max(b, __shfl_down(b, o));
  }
  if (lane == 0) { red_a[wid] = a; red_b[wid] = b; }
  __syncthreads();
  if (t == 0) {
    int na = min(min(red_a[0], red_a[1]), min(red_a[2], red_a[3]));
    int nb = max(max(red_b[0], red_b[1]), max(red_b[2], red_b[3]));
    bcast[0] = (na == 0x7fffffff) ? 1 : na;   // n
    bcast[1] = nb;                            // row max dur (j>=1)
  }
  __syncthreads();
  const int n       = bcast[0];
  const int dmaxall = bcast[1];

  // phase-2 reduce: denom = sum of d[j] for 1 <= j < n
  int dsum = 0;
#pragma unroll
  for (int k = 0; k < 4; ++k) {
    const int j0 = k * 1024 + t * 4;
#pragma unroll
    for (int m = 0; m < 4; ++m) {
      const int j = j0 + m;
      if (j >= 1 && j < n) dsum += d[k * 4 + m];
    }
  }
#pragma unroll
  for (int o = 32; o > 0; o >>= 1) dsum += __shfl_down(dsum, o);
  if (lane == 0) red_c[wid] = dsum;
  __syncthreads();
  if (t == 0) bcast[2] = red_c[0] + red_c[1] + red_c[2] + red_c[3];
  __syncthreads();
  const int denom = bcast[2];

  const float dni = fbcast[0];
  const float num = fbcast[1];
  const float denomf = (float)denom;
  const float rc = (n == 1) ? 1.0f
                            : fminf(1.0f, num / (denomf > 0.f ? denomf : 1.0f));
  const int delta = max(dmaxall, 1);
  const int dur0  = max(1, (int)dni - delta);

  float* __restrict__ rowout = out + (size_t)row * S_;
#pragma unroll
  for (int k = 0; k < 4; ++k) {
    const int j0 = k * 1024 + t * 4;
    float4 ov;
    float* o = reinterpret_cast<float*>(&ov);
#pragma unroll
    for (int m = 0; m < 4; ++m) {
      const int j = j0 + m;
      const int dd = d[k * 4 + m];
      int v;
      if (j == 0)      v = dur0;
      else if (j < n)  v = max(1, (int)truncf(rc * (float)dd));
      else             v = dd;
      o[m] = (float)v;
    }
    *reinterpret_cast<float4*>(rowout + j0) = ov;
  }
}

// ---------------------------------------------------------------------------
extern "C" void kernel_launch(void* const* d_in, const int* in_sizes, int n_in,
                              void* d_out, int out_size, void* d_ws, size_t ws_size,
                              hipStream_t stream) {
  const int*   idx    = (const int*)d_in[0];
  const float* ds     = (const float*)d_in[1];
  const float* sum_in = (const float*)d_in[2];
  const float* cnt_in = (const float*)d_in[3];
  const float* dur_in = (const float*)d_in[4];
  const float* rv     = (const float*)d_in[5];
  const float* dn     = (const float*)d_in[6];
  const int*   pad    = (const int*)d_in[7];

  float* out = (float*)d_out;

  float* part  = (float*)d_ws;                 // [512][1024] = 2 MB
  float* table = part + (size_t)NSCAT * 1024;  // [512]
  float* stats = table + P_;                   // [15] : sn[5], cn[5], raw[5]

  scatter_kernel<<<NSCAT, 256, 0, stream>>>(idx, ds, part);
  reduce_finalize_kernel<<<P_, 256, 0, stream>>>(part, sum_in, cnt_in, dur_in,
                                                 table, stats,
                                                 out + (size_t)B_ * S_);
  eval_kernel<<<1024, 256, 0, stream>>>(idx, table, stats, rv, dn, pad, out);
}